// Round 7
// baseline (421.801 us; speedup 1.0000x reference)
//
#include <hip/hip_runtime.h>
#include <math.h>

#define NN 50000
#define EE 800000
#define HH 256
#define CC 64
#define NPAD 50048          // NN rounded to 128
#define CHROWS 25088        // GEMM row chunk (multiple of 128)
#define NB 196              // scan blocks = ceil(NN/256)
#define QSCALE 0.09016843798f   // (1/16) * log2(e): folds 1/sqrt(H) and exp->exp2

typedef _Float16 f16x8 __attribute__((ext_vector_type(8)));
typedef _Float16 h2 __attribute__((ext_vector_type(2)));
typedef float f32x4 __attribute__((ext_vector_type(4)));

__device__ __forceinline__ float gelu_f(float x) {
    const float k0 = 0.7978845608028654f; // sqrt(2/pi)
    float x3 = x * x * x;
    return 0.5f * x * (1.0f + tanhf(k0 * (x + 0.044715f * x3)));
}

__device__ __forceinline__ unsigned short f2h(float x) {
    _Float16 h = (_Float16)x;
    return __builtin_bit_cast(unsigned short, h);
}

__device__ __forceinline__ float h2f_(unsigned short u) {
    return (float)__builtin_bit_cast(_Float16, u);
}

__device__ __forceinline__ h2 u2h2(unsigned int u) {
    return __builtin_bit_cast(h2, u);
}

__device__ __forceinline__ float fdot2_(h2 a, h2 b, float c) {
#if __has_builtin(__builtin_amdgcn_fdot2)
    return __builtin_amdgcn_fdot2(a, b, c, false);
#else
    return c + (float)a[0] * (float)b[0] + (float)a[1] * (float)b[1];
#endif
}

__device__ __forceinline__ void gld_lds16(const void* g, void* l) {
    __builtin_amdgcn_global_load_lds(
        (const __attribute__((address_space(1))) unsigned int*)g,
        (__attribute__((address_space(3))) unsigned int*)l,
        16, 0, 0);
}

// ---------------------------------------------------------------------------
// C[M,Nc] = act(A_f16[M,K] @ BT_f16[Nc,K]^T + bias); 128x128 tile, BK=64,
// 4 waves, 16x16x32 f16 MFMA. 2-phase software pipeline: double-buffered LDS,
// STAGE(next) issued before compute(cur), single barrier per k-step so the
// global_load_lds latency hides under the MFMA phase.
// STATS:  atomically accumulate per-row sum/sumsq of the output into st1/st2.
// LNFOLD: out = inv*raw - inv*mu*u[col] + bias[col], mu/inv from rs1/rs2.
// ---------------------------------------------------------------------------
template<int ACT, bool OUT_F16, bool STATS, bool LNFOLD>
__global__ __launch_bounds__(256) void mfma_gemm(
    const unsigned short* __restrict__ A,
    const unsigned short* __restrict__ BT,
    const float* __restrict__ bias,
    void* __restrict__ C,
    int M, int K, int Nc,
    float* __restrict__ st1, float* __restrict__ st2,
    const float* __restrict__ rs1, const float* __restrict__ rs2,
    const float* __restrict__ uvec)
{
    __shared__ __align__(16) unsigned char lds[65536]; // 2 bufs x (A 16K | B 16K)
    const int t    = threadIdx.x;
    const int lane = t & 63;
    const int wv   = t >> 6;
    const int wr   = wv >> 1, wc = wv & 1;
    const int row0 = blockIdx.y * 128;
    const int col0 = blockIdx.x * 128;

    f32x4 acc[4][4] = {};

    const int srow  = t >> 3;               // 0..31
    const int sslot = t & 7;
    const int schunk = sslot ^ (srow & 7);  // XOR-swizzled k-chunk slot

    const unsigned short* Ab = A  + (size_t)row0 * K;
    const unsigned short* Bb = BT + (size_t)col0 * K;

    auto stage = [&](int p, int k0) {
        #pragma unroll
        for (int i = 0; i < 4; ++i)
            gld_lds16(Ab + (size_t)(i * 32 + srow) * K + k0 + schunk * 8,
                      &lds[p * 32768 + i * 4096 + t * 16]);
        #pragma unroll
        for (int i = 0; i < 4; ++i)
            gld_lds16(Bb + (size_t)(i * 32 + srow) * K + k0 + schunk * 8,
                      &lds[p * 32768 + 16384 + i * 4096 + t * 16]);
    };

    stage(0, 0);
    __syncthreads();                       // drain prologue stage
    int cur = 0;
    for (int k0 = 0; k0 < K; k0 += 64) {
        if (k0 + 64 < K) stage(cur ^ 1, k0 + 64);   // prefetch next k-step
        const unsigned bA = cur * 32768;
        const unsigned bB = bA + 16384;
        #pragma unroll
        for (int kk = 0; kk < 2; ++kk) {
            f16x8 af[4], bf[4];
            #pragma unroll
            for (int m = 0; m < 4; ++m) {
                int r  = wr * 64 + m * 16 + (lane & 15);
                int ch = (kk * 4 + (lane >> 4)) ^ (r & 7);
                af[m] = *reinterpret_cast<const f16x8*>(&lds[bA + r * 128 + ch * 16]);
            }
            #pragma unroll
            for (int n = 0; n < 4; ++n) {
                int r  = wc * 64 + n * 16 + (lane & 15);
                int ch = (kk * 4 + (lane >> 4)) ^ (r & 7);
                bf[n] = *reinterpret_cast<const f16x8*>(&lds[bB + r * 128 + ch * 16]);
            }
            #pragma unroll
            for (int m = 0; m < 4; ++m)
                #pragma unroll
                for (int n = 0; n < 4; ++n)
                    acc[m][n] = __builtin_amdgcn_mfma_f32_16x16x32_f16(
                        af[m], bf[n], acc[m][n], 0, 0, 0);
        }
        __syncthreads();   // drains next-step stage (overlapped with MFMA above)
        cur ^= 1;
    }

    float bv[4], uv_[4];
    #pragma unroll
    for (int n = 0; n < 4; ++n) {
        int col = col0 + wc * 64 + n * 16 + (lane & 15);
        bv[n] = bias[col];
        if (LNFOLD) uv_[n] = uvec[col];
    }

    #pragma unroll
    for (int m = 0; m < 4; ++m) {
        #pragma unroll
        for (int rg = 0; rg < 4; ++rg) {
            int row = row0 + wr * 64 + m * 16 + (lane >> 4) * 4 + rg;
            float inv = 0.f, nmu = 0.f;
            if (LNFOLD) {
                float S1 = rs1[row], S2 = rs2[row];
                float mu = S1 * (1.0f / HH);
                float var = S2 * (1.0f / HH) - mu * mu;
                inv = rsqrtf(var + 1e-5f);
                nmu = inv * mu;
            }
            float s1l = 0.f, s2l = 0.f;
            #pragma unroll
            for (int n = 0; n < 4; ++n) {
                float v;
                if (LNFOLD) v = fmaf(inv, acc[m][n][rg], fmaf(-nmu, uv_[n], bv[n]));
                else        v = acc[m][n][rg] + bv[n];
                if (ACT) v = gelu_f(v);
                if (STATS) { s1l += v; s2l += v * v; }
                if (row < M) {
                    int col = col0 + wc * 64 + n * 16 + (lane & 15);
                    if (OUT_F16) ((unsigned short*)C)[(size_t)row * Nc + col] = f2h(v);
                    else         ((float*)C)[(size_t)row * Nc + col] = v;
                }
            }
            if (STATS) {
                #pragma unroll
                for (int o = 1; o < 16; o <<= 1) {
                    s1l += __shfl_xor(s1l, o);
                    s2l += __shfl_xor(s2l, o);
                }
                if ((lane & 15) == 0 && row < M) {
                    atomicAdd(&st1[row], s1l);
                    atomicAdd(&st2[row], s2l);
                }
            }
        }
    }
}

// ---------------------------------------------------------------------------
// prep mega-kernel: f2h(embedding), f2h(scores), W1T, W2T, WlrT (g-folded,
// q-half scaled by QSCALE), k2 table, u/v fold vectors — one launch.
// ---------------------------------------------------------------------------
#define PB0 12500                 // embedding f2h   (NN*HH/4/256)
#define PB1 (PB0 + 3125)          // scores f2h
#define PB2 (PB1 + 1024)          // W1T
#define PB3 (PB2 + 1024)          // W2T
#define PB4 (PB3 + 256)           // WlT'
#define PB5 (PB4 + 256)           // WrT'
#define PB6 (PB5 + 3)             // k2
#define PB7 (PB6 + 2)             // u/v
__global__ __launch_bounds__(256) void prep_kernel(
    const float* __restrict__ embedding, const float* __restrict__ scores,
    const float* __restrict__ W1, const float* __restrict__ W2,
    const float* __restrict__ Wl, const float* __restrict__ Wr,
    const float* __restrict__ ln_g, const float* __restrict__ ln_b,
    const float* __restrict__ bl, const float* __restrict__ br,
    const float* __restrict__ We, const float* __restrict__ be,
    const float* __restrict__ emb_table,
    unsigned short* __restrict__ embA, unsigned short* __restrict__ scoresb,
    unsigned short* __restrict__ W1T, unsigned short* __restrict__ W2T,
    unsigned short* __restrict__ WlrT, unsigned short* __restrict__ k2t,
    float* __restrict__ uvec, float* __restrict__ vvec)
{
    const int gb = blockIdx.x, t = threadIdx.x;
    if (gb < PB0) {
        int i = gb * 256 + t;
        float4 v = reinterpret_cast<const float4*>(embedding)[i];
        ushort4 o; o.x = f2h(v.x); o.y = f2h(v.y); o.z = f2h(v.z); o.w = f2h(v.w);
        reinterpret_cast<ushort4*>(embA)[i] = o;
    } else if (gb < PB1) {
        int i = (gb - PB0) * 256 + t;
        float4 v = reinterpret_cast<const float4*>(scores)[i];
        ushort4 o; o.x = f2h(v.x); o.y = f2h(v.y); o.z = f2h(v.z); o.w = f2h(v.w);
        reinterpret_cast<ushort4*>(scoresb)[i] = o;
    } else if (gb < PB2) {
        int o = (gb - PB1) * 256 + t;          // W1T[c][r], c=o>>8
        int c = o >> 8, r = o & 255;
        W1T[o] = f2h(W1[r * 1024 + c]);
    } else if (gb < PB3) {
        int o = (gb - PB2) * 256 + t;          // W2T[c][r], c=o>>10
        int c = o >> 10, r = o & 1023;
        W2T[o] = f2h(W2[r * 256 + c]);
    } else if (gb < PB4) {
        int o = (gb - PB3) * 256 + t;
        int c = o >> 8, r = o & 255;
        WlrT[o] = f2h(Wl[r * 256 + c] * ln_g[r] * QSCALE);
    } else if (gb < PB5) {
        int o = (gb - PB4) * 256 + t;
        int c = o >> 8, r = o & 255;
        WlrT[65536 + o] = f2h(Wr[r * 256 + c] * ln_g[r]);
    } else if (gb < PB6) {
        int ty = gb - PB5;
        float a = be[t];
        #pragma unroll
        for (int f = 0; f < 20; ++f)
            a += gelu_f(emb_table[ty * 20 + f]) * We[f * 256 + t];
        k2t[ty * 256 + t] = f2h(a);
    } else {
        int c = (gb - PB6) * 256 + t;          // 0..511
        int cc = c & 255;
        const float* W = (c < 256) ? Wl : Wr;
        float u = 0.f, v = 0.f;
        for (int j = 0; j < 256; ++j) {
            float w = W[j * 256 + cc];
            u += ln_g[j] * w;
            v += ln_b[j] * w;
        }
        float sc = (c < 256) ? QSCALE : 1.0f;
        uvec[c] = u * sc;
        vvec[c] = (v + ((c < 256) ? bl[cc] : br[cc])) * sc;
    }
}

// ---- CSR build ----
__global__ void hist_kernel(const int* __restrict__ dst, int* __restrict__ cnt)
{
    int e = blockIdx.x * 256 + threadIdx.x;
    if (e < EE) atomicAdd(&cnt[dst[e]], 1);
}

__global__ __launch_bounds__(256) void scan_part(
    const int* __restrict__ cnt, int* __restrict__ off, int* __restrict__ bsum)
{
    int b = blockIdx.x, t = threadIdx.x;
    int idx = b * 256 + t;
    int v = (idx < NN) ? cnt[idx] : 0;
    int inc = v;
    #pragma unroll
    for (int o = 1; o < 64; o <<= 1) {
        int u = __shfl_up(inc, o);
        if ((t & 63) >= o) inc += u;
    }
    __shared__ int wt[4];
    if ((t & 63) == 63) wt[t >> 6] = inc;
    __syncthreads();
    int wo = 0;
    #pragma unroll
    for (int w = 0; w < 4; ++w) if (w < (t >> 6)) wo += wt[w];
    if (idx < NN) off[idx] = wo + inc - v;
    if (t == 255) bsum[b] = wo + inc;
}

__global__ __launch_bounds__(256) void scan_sums(int* __restrict__ bsum)
{
    int t = threadIdx.x;
    int v = (t < NB) ? bsum[t] : 0;
    int inc = v;
    #pragma unroll
    for (int o = 1; o < 64; o <<= 1) {
        int u = __shfl_up(inc, o);
        if ((t & 63) >= o) inc += u;
    }
    __shared__ int wt[4];
    if ((t & 63) == 63) wt[t >> 6] = inc;
    __syncthreads();
    int wo = 0;
    #pragma unroll
    for (int w = 0; w < 4; ++w) if (w < (t >> 6)) wo += wt[w];
    if (t < NB) bsum[t] = wo + inc - v;
}

__global__ void scan_add(int* __restrict__ off, const int* __restrict__ bsum,
                         int* __restrict__ cur)
{
    int b = blockIdx.x, t = threadIdx.x;
    int idx = b * 256 + t;
    if (idx < NN) {
        int o = off[idx] + bsum[b];
        off[idx] = o;
        cur[idx] = o;
    }
    if (idx == 0) off[NN] = EE;
}

// pack entry = (src << 10) | ty  -> byte offset of the qk row, type in low bits
__global__ void fill_kernel(const int* __restrict__ src, const int* __restrict__ dst,
                            const int* __restrict__ typ, int* __restrict__ cur,
                            unsigned int* __restrict__ pack)
{
    int e = blockIdx.x * 256 + threadIdx.x;
    if (e < 8) pack[EE + e] = 0;  // pad slots for unconditional 4-wide reads
    if (e >= EE) return;
    int pos = atomicAdd(&cur[dst[e]], 1);
    pack[pos] = ((unsigned int)src[e] << 10) | (unsigned int)typ[e];
}

// ---------------------------------------------------------------------------
// fused per-dst attention: one wave per node; 4 edges per iteration, two
// independent 32-lane dot/reduce chains (ILP), v_dot2 f16 dots, exp2-domain
// online softmax with one rescale per 4 edges, depth-1 prefetch.
// ---------------------------------------------------------------------------
__global__ __launch_bounds__(256) void fused_edge_kernel(
    const unsigned short* __restrict__ qk,      // f16 [NPAD][512]: [q*QSCALE | k1]
    const unsigned short* __restrict__ k2t,     // f16 [3][256]
    const int* __restrict__ off, const unsigned int* __restrict__ pack,
    const unsigned short* __restrict__ scoresb, // f16 [NN][64]
    float* __restrict__ out)
{
    const int t = threadIdx.x, lane = t & 63;
    const int sub = lane & 31;
    const int g = lane >> 5;
    const int d = blockIdx.x * 4 + (t >> 6);
    if (d >= NN) return;
    const int beg = off[d], end = off[d + 1];
    if (beg == end) { out[(size_t)d * CC + lane] = 0.f; return; }

    const char* qkb = (const char*)qk;

    // q slice: 8 f16 at dims [sub*8, sub*8+8) (duplicated across wave halves)
    uint4 qv = *reinterpret_cast<const uint4*>(qkb + (size_t)d * 1024 + sub * 16);
    h2 q0 = u2h2(qv.x), q1 = u2h2(qv.y), q2 = u2h2(qv.z), q3 = u2h2(qv.w);

    auto dot = [&](uint4 kv) {
        float a = fdot2_(q0, u2h2(kv.x), 0.f);
        a = fdot2_(q1, u2h2(kv.y), a);
        a = fdot2_(q2, u2h2(kv.z), a);
        a = fdot2_(q3, u2h2(kv.w), a);
        return a;
    };

    // qe[ty] = q . k2t[ty] (exp2-domain via q scaling)
    float qe0, qe1, qe2;
    {
        uint4 k0v = *reinterpret_cast<const uint4*>((const char*)k2t + 0 * 512 + sub * 16);
        uint4 k1v = *reinterpret_cast<const uint4*>((const char*)k2t + 1 * 512 + sub * 16);
        uint4 k2v = *reinterpret_cast<const uint4*>((const char*)k2t + 2 * 512 + sub * 16);
        qe0 = dot(k0v); qe1 = dot(k1v); qe2 = dot(k2v);
        #pragma unroll
        for (int o = 1; o < 32; o <<= 1) {
            qe0 += __shfl_xor(qe0, o);
            qe1 += __shfl_xor(qe1, o);
            qe2 += __shfl_xor(qe2, o);
        }
    }
    auto qsel = [&](unsigned pk) {
        int ty = pk & 3;
        return (ty == 0) ? qe0 : (ty == 1) ? qe1 : qe2;
    };

    // prologue: load quad {beg .. beg+3} (padded reads are safe & masked)
    unsigned pk0 = pack[beg],     pk1 = pack[beg + 1];
    unsigned pk2 = pack[beg + 2], pk3 = pack[beg + 3];
    uint4 kvX = *reinterpret_cast<const uint4*>(qkb + ((g ? pk1 : pk0) & ~3u) + 512 + sub * 16);
    uint4 kvY = *reinterpret_cast<const uint4*>(qkb + ((g ? pk3 : pk2) & ~3u) + 512 + sub * 16);
    float sc0 = h2f_(scoresb[((pk0 & ~3u) >> 4) + lane]);
    float sc1 = h2f_(scoresb[((pk1 & ~3u) >> 4) + lane]);
    float sc2 = h2f_(scoresb[((pk2 & ~3u) >> 4) + lane]);
    float sc3 = h2f_(scoresb[((pk3 & ~3u) >> 4) + lane]);

    float m = -INFINITY, s = 0.f, acc = 0.f;

    for (int i = beg; i < end; i += 4) {
        int inext = (i + 4 < end) ? i + 4 : i;
        unsigned npk0 = pack[inext],     npk1 = pack[inext + 1];
        unsigned npk2 = pack[inext + 2], npk3 = pack[inext + 3];
        uint4 nkX = *reinterpret_cast<const uint4*>(qkb + ((g ? npk1 : npk0) & ~3u) + 512 + sub * 16);
        uint4 nkY = *reinterpret_cast<const uint4*>(qkb + ((g ? npk3 : npk2) & ~3u) + 512 + sub * 16);
        float ns0 = h2f_(scoresb[((npk0 & ~3u) >> 4) + lane]);
        float ns1 = h2f_(scoresb[((npk1 & ~3u) >> 4) + lane]);
        float ns2 = h2f_(scoresb[((npk2 & ~3u) >> 4) + lane]);
        float ns3 = h2f_(scoresb[((npk3 & ~3u) >> 4) + lane]);

        float a1 = dot(kvX);            // g=0: e0, g=1: e1
        float a2 = dot(kvY);            // g=0: e2, g=1: e3
        #pragma unroll
        for (int o = 1; o < 32; o <<= 1) {
            a1 += __shfl_xor(a1, o);
            a2 += __shfl_xor(a2, o);
        }
        float o1 = __shfl_xor(a1, 32);
        float o2 = __shfl_xor(a2, 32);
        float aA = (g ? o1 : a1) + qsel(pk0);
        float aB = (g ? a1 : o1) + qsel(pk1);
        float aC = (g ? o2 : a2) + qsel(pk2);
        float aD = (g ? a2 : o2) + qsel(pk3);
        if (i + 1 >= end) aB = -INFINITY;
        if (i + 2 >= end) aC = -INFINITY;
        if (i + 3 >= end) aD = -INFINITY;

        float nm = fmaxf(fmaxf(m, fmaxf(aA, aB)), fmaxf(aC, aD));
        float c_ = exp2f(m - nm);       // first iter: exp2(-inf)=0
        float w0 = exp2f(aA - nm);
        float w1 = exp2f(aB - nm);
        float w2 = exp2f(aC - nm);
        float w3 = exp2f(aD - nm);
        s = s * c_ + (w0 + w1) + (w2 + w3);
        acc = fmaf(acc, c_, fmaf(w0, sc0, fmaf(w1, sc1, fmaf(w2, sc2, w3 * sc3))));
        m = nm;

        pk0 = npk0; pk1 = npk1; pk2 = npk2; pk3 = npk3;
        kvX = nkX; kvY = nkY;
        sc0 = ns0; sc1 = ns1; sc2 = ns2; sc3 = ns3;
    }
    out[(size_t)d * CC + lane] = acc / s;
}

extern "C" void kernel_launch(void* const* d_in, const int* in_sizes, int n_in,
                              void* d_out, int out_size, void* d_ws, size_t ws_size,
                              hipStream_t stream) {
    const float* embedding = (const float*)d_in[0];
    const float* scores    = (const float*)d_in[1];
    const int*   src       = (const int*)d_in[2];
    const int*   dst       = (const int*)d_in[3];
    const int*   typ       = (const int*)d_in[4];
    const float* W1  = (const float*)d_in[5];
    const float* b1  = (const float*)d_in[6];
    const float* W2  = (const float*)d_in[7];
    const float* b2  = (const float*)d_in[8];
    const float* ln_g = (const float*)d_in[9];
    const float* ln_b = (const float*)d_in[10];
    const float* Wl  = (const float*)d_in[11];
    const float* bl  = (const float*)d_in[12];
    const float* Wr  = (const float*)d_in[13];
    const float* br  = (const float*)d_in[14];
    const float* We  = (const float*)d_in[15];
    const float* be  = (const float*)d_in[16];
    const float* emb_table = (const float*)d_in[17];
    float* out = (float*)d_out;
    (void)in_sizes; (void)n_in; (void)out_size; (void)ws_size;

    // ---- workspace carve-up (256-aligned chunks) ----
    char* w = (char*)d_ws;
    auto take = [&](size_t bytes) {
        char* p = w;
        w += (bytes + 255) & ~(size_t)255;
        return p;
    };
    unsigned short* embA = (unsigned short*)take((size_t)NPAD * HH * 2);
    unsigned short* hpre = (unsigned short*)take((size_t)NPAD * HH * 2);
    unsigned short* qk   = (unsigned short*)take((size_t)NPAD * 512 * 2);
    unsigned short* Gch  = (unsigned short*)take((size_t)CHROWS * 4 * HH * 2);
    unsigned short* W1T  = (unsigned short*)take((size_t)4 * HH * HH * 2);
    unsigned short* W2T  = (unsigned short*)take((size_t)HH * 4 * HH * 2);
    unsigned short* WlrT = (unsigned short*)take((size_t)512 * HH * 2);
    unsigned short* k2t  = (unsigned short*)take(2048);
    unsigned short* scoresb = (unsigned short*)take((size_t)NN * CC * 2);
    float*          uvec = (float*)take(512 * 4);
    float*          vvec = (float*)take(512 * 4);
    int*            cnt  = (int*)take((size_t)NPAD * 4);   // NPAD*4 is 256-aligned
    float*          st1  = (float*)take((size_t)NPAD * 4); // contiguous with cnt
    float*          st2  = (float*)take((size_t)NPAD * 4); // contiguous with st1
    int*            offb = (int*)take((size_t)(NN + 1) * 4);
    int*            cur  = (int*)take((size_t)NN * 4);
    int*            bsum = (int*)take(256 * 4);
    unsigned int*   pack = (unsigned int*)take((size_t)EE * 4 + 64);

    // zero cnt + st1 + st2 in one memset (contiguous NPAD-sized chunks)
    hipMemsetAsync(cnt, 0, (size_t)3 * NPAD * 4, stream);

    // ---- one prep launch: conversions, transposes, k2, u/v ----
    prep_kernel<<<PB7, 256, 0, stream>>>(
        embedding, scores, W1, W2, Wl, Wr, ln_g, ln_b, bl, br, We, be, emb_table,
        embA, scoresb, W1T, W2T, WlrT, k2t, uvec, vvec);

    // ---- CSR build ----
    hist_kernel<<<(EE + 255) / 256, 256, 0, stream>>>(dst, cnt);
    scan_part<<<NB, 256, 0, stream>>>(cnt, offb, bsum);
    scan_sums<<<1, 256, 0, stream>>>(bsum);
    scan_add<<<NB, 256, 0, stream>>>(offb, bsum, cur);
    fill_kernel<<<(EE + 255) / 256, 256, 0, stream>>>(src, dst, typ, cur, pack);

    // ---- MLP: hpre = gelu(X@W1+b1)@W2+b2 (f16), W2 also emits row stats ----
    for (int r0 = 0; r0 < NN; r0 += CHROWS) {
        int mr = (NN - r0 < CHROWS) ? (NN - r0) : CHROWS;
        int gy = (mr + 127) / 128;
        dim3 g1(4 * HH / 128, gy);
        mfma_gemm<1, true, false, false><<<g1, 256, 0, stream>>>(
            embA + (size_t)r0 * HH, W1T, b1, Gch, mr, HH, 4 * HH,
            nullptr, nullptr, nullptr, nullptr, nullptr);
        dim3 g2(HH / 128, gy);
        mfma_gemm<0, true, true, false><<<g2, 256, 0, stream>>>(
            Gch, W2T, b2, hpre + (size_t)r0 * HH, mr, 4 * HH, HH,
            st1 + r0, st2 + r0, nullptr, nullptr, nullptr);
    }

    // ---- q|k1 projection with fused LayerNorm (LN folded into epilogue) ----
    dim3 gq(512 / 128, (NN + 127) / 128);
    mfma_gemm<0, true, false, true><<<gq, 256, 0, stream>>>(
        hpre, WlrT, vvec, qk, NN, HH, 512,
        nullptr, nullptr, st1, st2, uvec);

    // ---- fused edge phase ----
    fused_edge_kernel<<<(NN + 3) / 4, 256, 0, stream>>>(qk, k2t, offb, pack, scoresb, out);
}

// Round 8
// 401.456 us; speedup vs baseline: 1.0507x; 1.0507x over previous
//
#include <hip/hip_runtime.h>
#include <math.h>

#define NN 50000
#define EE 800000
#define HH 256
#define CC 64
#define NPAD 50048          // NN rounded to 128
#define NB 196              // scan blocks = ceil(NN/256)
#define QSCALE 0.09016843798f   // (1/16) * log2(e): folds 1/sqrt(H) and exp->exp2

typedef _Float16 f16x8 __attribute__((ext_vector_type(8)));
typedef _Float16 h2 __attribute__((ext_vector_type(2)));
typedef float f32x4 __attribute__((ext_vector_type(4)));

__device__ __forceinline__ float gelu_f(float x) {
    const float k0 = 0.7978845608028654f; // sqrt(2/pi)
    float x3 = x * x * x;
    return 0.5f * x * (1.0f + tanhf(k0 * (x + 0.044715f * x3)));
}

__device__ __forceinline__ unsigned short f2h(float x) {
    _Float16 h = (_Float16)x;
    return __builtin_bit_cast(unsigned short, h);
}

__device__ __forceinline__ float h2f_(unsigned short u) {
    return (float)__builtin_bit_cast(_Float16, u);
}

__device__ __forceinline__ h2 u2h2(unsigned int u) {
    return __builtin_bit_cast(h2, u);
}

__device__ __forceinline__ float fdot2_(h2 a, h2 b, float c) {
#if __has_builtin(__builtin_amdgcn_fdot2)
    return __builtin_amdgcn_fdot2(a, b, c, false);
#else
    return c + (float)a[0] * (float)b[0] + (float)a[1] * (float)b[1];
#endif
}

__device__ __forceinline__ void gld_lds16(const void* g, void* l) {
    __builtin_amdgcn_global_load_lds(
        (const __attribute__((address_space(1))) unsigned int*)g,
        (__attribute__((address_space(3))) unsigned int*)l,
        16, 0, 0);
}

// ---------------------------------------------------------------------------
// C[M,Nc] = act(A_f16[M,K] @ BT_f16[Nc,K]^T + bias); 128x128 tile, BK=64,
// 4 waves, 16x16x32 f16 MFMA, global_load_lds, XOR-swizzled LDS.
// (R6 structure: 32KB LDS, ~5 blocks/CU — measured better than 64KB dbuf.)
// STATS:  atomically accumulate per-row sum/sumsq of the output into st1/st2.
// LNFOLD: out = inv*raw - inv*mu*u[col] + bias[col], mu/inv from rs1/rs2.
// ---------------------------------------------------------------------------
template<int ACT, bool OUT_F16, bool STATS, bool LNFOLD>
__global__ __launch_bounds__(256) void mfma_gemm(
    const unsigned short* __restrict__ A,
    const unsigned short* __restrict__ BT,
    const float* __restrict__ bias,
    void* __restrict__ C,
    int M, int K, int Nc,
    float* __restrict__ st1, float* __restrict__ st2,
    const float* __restrict__ rs1, const float* __restrict__ rs2,
    const float* __restrict__ uvec)
{
    __shared__ __align__(16) unsigned char lds[32768]; // A: [0,16K), B: [16K,32K)
    const int t    = threadIdx.x;
    const int lane = t & 63;
    const int wv   = t >> 6;
    const int wr   = wv >> 1, wc = wv & 1;
    const int row0 = blockIdx.y * 128;
    const int col0 = blockIdx.x * 128;

    f32x4 acc[4][4] = {};

    const int srow  = t >> 3;               // 0..31
    const int sslot = t & 7;
    const int schunk = sslot ^ (srow & 7);  // XOR-swizzled k-chunk slot

    const unsigned short* Ab = A  + (size_t)row0 * K;
    const unsigned short* Bb = BT + (size_t)col0 * K;

    for (int k0 = 0; k0 < K; k0 += 64) {
        #pragma unroll
        for (int i = 0; i < 4; ++i)
            gld_lds16(Ab + (size_t)(i * 32 + srow) * K + k0 + schunk * 8,
                      &lds[i * 4096 + t * 16]);
        #pragma unroll
        for (int i = 0; i < 4; ++i)
            gld_lds16(Bb + (size_t)(i * 32 + srow) * K + k0 + schunk * 8,
                      &lds[16384 + i * 4096 + t * 16]);
        __syncthreads();

        #pragma unroll
        for (int kk = 0; kk < 2; ++kk) {
            f16x8 af[4], bf[4];
            #pragma unroll
            for (int m = 0; m < 4; ++m) {
                int r  = wr * 64 + m * 16 + (lane & 15);
                int ch = (kk * 4 + (lane >> 4)) ^ (r & 7);
                af[m] = *reinterpret_cast<const f16x8*>(&lds[r * 128 + ch * 16]);
            }
            #pragma unroll
            for (int n = 0; n < 4; ++n) {
                int r  = wc * 64 + n * 16 + (lane & 15);
                int ch = (kk * 4 + (lane >> 4)) ^ (r & 7);
                bf[n] = *reinterpret_cast<const f16x8*>(&lds[16384 + r * 128 + ch * 16]);
            }
            #pragma unroll
            for (int m = 0; m < 4; ++m)
                #pragma unroll
                for (int n = 0; n < 4; ++n)
                    acc[m][n] = __builtin_amdgcn_mfma_f32_16x16x32_f16(
                        af[m], bf[n], acc[m][n], 0, 0, 0);
        }
        __syncthreads();
    }

    float bv[4], uv_[4];
    #pragma unroll
    for (int n = 0; n < 4; ++n) {
        int col = col0 + wc * 64 + n * 16 + (lane & 15);
        bv[n] = bias[col];
        if (LNFOLD) uv_[n] = uvec[col];
    }

    #pragma unroll
    for (int m = 0; m < 4; ++m) {
        #pragma unroll
        for (int rg = 0; rg < 4; ++rg) {
            int row = row0 + wr * 64 + m * 16 + (lane >> 4) * 4 + rg;
            float inv = 0.f, nmu = 0.f;
            if (LNFOLD) {
                float S1 = rs1[row], S2 = rs2[row];
                float mu = S1 * (1.0f / HH);
                float var = S2 * (1.0f / HH) - mu * mu;
                inv = rsqrtf(var + 1e-5f);
                nmu = inv * mu;
            }
            float s1l = 0.f, s2l = 0.f;
            #pragma unroll
            for (int n = 0; n < 4; ++n) {
                float v;
                if (LNFOLD) v = fmaf(inv, acc[m][n][rg], fmaf(-nmu, uv_[n], bv[n]));
                else        v = acc[m][n][rg] + bv[n];
                if (ACT) v = gelu_f(v);
                if (STATS) { s1l += v; s2l += v * v; }
                if (row < M) {
                    int col = col0 + wc * 64 + n * 16 + (lane & 15);
                    if (OUT_F16) ((unsigned short*)C)[(size_t)row * Nc + col] = f2h(v);
                    else         ((float*)C)[(size_t)row * Nc + col] = v;
                }
            }
            if (STATS) {
                #pragma unroll
                for (int o = 1; o < 16; o <<= 1) {
                    s1l += __shfl_xor(s1l, o);
                    s2l += __shfl_xor(s2l, o);
                }
                if ((lane & 15) == 0 && row < M) {
                    atomicAdd(&st1[row], s1l);
                    atomicAdd(&st2[row], s2l);
                }
            }
        }
    }
}

// ---------------------------------------------------------------------------
// prep mega-kernel: f2h(embedding), f2h(scores), W1T, W2T, WlrT (g-folded,
// q-half scaled by QSCALE), k2 table, u/v fold vectors — one launch.
// ---------------------------------------------------------------------------
#define PB0 12500                 // embedding f2h   (NN*HH/4/256)
#define PB1 (PB0 + 3125)          // scores f2h
#define PB2 (PB1 + 1024)          // W1T
#define PB3 (PB2 + 1024)          // W2T
#define PB4 (PB3 + 256)           // WlT'
#define PB5 (PB4 + 256)           // WrT'
#define PB6 (PB5 + 3)             // k2
#define PB7 (PB6 + 2)             // u/v
__global__ __launch_bounds__(256) void prep_kernel(
    const float* __restrict__ embedding, const float* __restrict__ scores,
    const float* __restrict__ W1, const float* __restrict__ W2,
    const float* __restrict__ Wl, const float* __restrict__ Wr,
    const float* __restrict__ ln_g, const float* __restrict__ ln_b,
    const float* __restrict__ bl, const float* __restrict__ br,
    const float* __restrict__ We, const float* __restrict__ be,
    const float* __restrict__ emb_table,
    unsigned short* __restrict__ embA, unsigned short* __restrict__ scoresb,
    unsigned short* __restrict__ W1T, unsigned short* __restrict__ W2T,
    unsigned short* __restrict__ WlrT, unsigned short* __restrict__ k2t,
    float* __restrict__ uvec, float* __restrict__ vvec)
{
    const int gb = blockIdx.x, t = threadIdx.x;
    if (gb < PB0) {
        int i = gb * 256 + t;
        float4 v = reinterpret_cast<const float4*>(embedding)[i];
        ushort4 o; o.x = f2h(v.x); o.y = f2h(v.y); o.z = f2h(v.z); o.w = f2h(v.w);
        reinterpret_cast<ushort4*>(embA)[i] = o;
    } else if (gb < PB1) {
        int i = (gb - PB0) * 256 + t;
        float4 v = reinterpret_cast<const float4*>(scores)[i];
        ushort4 o; o.x = f2h(v.x); o.y = f2h(v.y); o.z = f2h(v.z); o.w = f2h(v.w);
        reinterpret_cast<ushort4*>(scoresb)[i] = o;
    } else if (gb < PB2) {
        int o = (gb - PB1) * 256 + t;          // W1T[c][r], c=o>>8
        int c = o >> 8, r = o & 255;
        W1T[o] = f2h(W1[r * 1024 + c]);
    } else if (gb < PB3) {
        int o = (gb - PB2) * 256 + t;          // W2T[c][r], c=o>>10
        int c = o >> 10, r = o & 1023;
        W2T[o] = f2h(W2[r * 256 + c]);
    } else if (gb < PB4) {
        int o = (gb - PB3) * 256 + t;
        int c = o >> 8, r = o & 255;
        WlrT[o] = f2h(Wl[r * 256 + c] * ln_g[r] * QSCALE);
    } else if (gb < PB5) {
        int o = (gb - PB4) * 256 + t;
        int c = o >> 8, r = o & 255;
        WlrT[65536 + o] = f2h(Wr[r * 256 + c] * ln_g[r]);
    } else if (gb < PB6) {
        int ty = gb - PB5;
        float a = be[t];
        #pragma unroll
        for (int f = 0; f < 20; ++f)
            a += gelu_f(emb_table[ty * 20 + f]) * We[f * 256 + t];
        k2t[ty * 256 + t] = f2h(a);
    } else {
        int c = (gb - PB6) * 256 + t;          // 0..511
        int cc = c & 255;
        const float* W = (c < 256) ? Wl : Wr;
        float u = 0.f, v = 0.f;
        for (int j = 0; j < 256; ++j) {
            float w = W[j * 256 + cc];
            u += ln_g[j] * w;
            v += ln_b[j] * w;
        }
        float sc = (c < 256) ? QSCALE : 1.0f;
        uvec[c] = u * sc;
        vvec[c] = (v + ((c < 256) ? bl[cc] : br[cc])) * sc;
    }
}

// ---- CSR build ----
__global__ void hist_kernel(const int* __restrict__ dst, int* __restrict__ cnt)
{
    int e = blockIdx.x * 256 + threadIdx.x;
    if (e < EE) atomicAdd(&cnt[dst[e]], 1);
}

__global__ __launch_bounds__(256) void scan_part(
    const int* __restrict__ cnt, int* __restrict__ off, int* __restrict__ bsum)
{
    int b = blockIdx.x, t = threadIdx.x;
    int idx = b * 256 + t;
    int v = (idx < NN) ? cnt[idx] : 0;
    int inc = v;
    #pragma unroll
    for (int o = 1; o < 64; o <<= 1) {
        int u = __shfl_up(inc, o);
        if ((t & 63) >= o) inc += u;
    }
    __shared__ int wt[4];
    if ((t & 63) == 63) wt[t >> 6] = inc;
    __syncthreads();
    int wo = 0;
    #pragma unroll
    for (int w = 0; w < 4; ++w) if (w < (t >> 6)) wo += wt[w];
    if (idx < NN) off[idx] = wo + inc - v;
    if (t == 255) bsum[b] = wo + inc;
}

__global__ __launch_bounds__(256) void scan_sums(int* __restrict__ bsum)
{
    int t = threadIdx.x;
    int v = (t < NB) ? bsum[t] : 0;
    int inc = v;
    #pragma unroll
    for (int o = 1; o < 64; o <<= 1) {
        int u = __shfl_up(inc, o);
        if ((t & 63) >= o) inc += u;
    }
    __shared__ int wt[4];
    if ((t & 63) == 63) wt[t >> 6] = inc;
    __syncthreads();
    int wo = 0;
    #pragma unroll
    for (int w = 0; w < 4; ++w) if (w < (t >> 6)) wo += wt[w];
    if (t < NB) bsum[t] = wo + inc - v;
}

__global__ void scan_add(int* __restrict__ off, const int* __restrict__ bsum,
                         int* __restrict__ cur)
{
    int b = blockIdx.x, t = threadIdx.x;
    int idx = b * 256 + t;
    if (idx < NN) {
        int o = off[idx] + bsum[b];
        off[idx] = o;
        cur[idx] = o;
    }
    if (idx == 0) off[NN] = EE;
}

// pack entry = (src << 10) | ty  -> byte offset of the qk row, type in low bits
__global__ void fill_kernel(const int* __restrict__ src, const int* __restrict__ dst,
                            const int* __restrict__ typ, int* __restrict__ cur,
                            unsigned int* __restrict__ pack)
{
    int e = blockIdx.x * 256 + threadIdx.x;
    if (e < 8) pack[EE + e] = 0;  // pad slots for unconditional paired reads
    if (e >= EE) return;
    int pos = atomicAdd(&cur[dst[e]], 1);
    pack[pos] = ((unsigned int)src[e] << 10) | (unsigned int)typ[e];
}

// ---------------------------------------------------------------------------
// fused per-dst attention (R6 structure): one wave per node; 2 edges in
// flight with a shared 32-lane dot/reduce, v_dot2 f16 dots, exp2-domain
// online softmax, qe prologue, depth-1 prefetch.
// ---------------------------------------------------------------------------
__global__ __launch_bounds__(256) void fused_edge_kernel(
    const unsigned short* __restrict__ qk,      // f16 [NPAD][512]: [q*QSCALE | k1]
    const unsigned short* __restrict__ k2t,     // f16 [3][256]
    const int* __restrict__ off, const unsigned int* __restrict__ pack,
    const unsigned short* __restrict__ scoresb, // f16 [NN][64]
    float* __restrict__ out)
{
    const int t = threadIdx.x, lane = t & 63;
    const int sub = lane & 31;
    const int g = lane >> 5;
    const int d = blockIdx.x * 4 + (t >> 6);
    if (d >= NN) return;
    const int beg = off[d], end = off[d + 1];
    if (beg == end) { out[(size_t)d * CC + lane] = 0.f; return; }

    const char* qkb = (const char*)qk;

    // q slice: 8 f16 at dims [sub*8, sub*8+8) (duplicated across wave halves)
    uint4 qv = *reinterpret_cast<const uint4*>(qkb + (size_t)d * 1024 + sub * 16);
    h2 q0 = u2h2(qv.x), q1 = u2h2(qv.y), q2 = u2h2(qv.z), q3 = u2h2(qv.w);

    auto dot = [&](uint4 kv) {
        float a = fdot2_(q0, u2h2(kv.x), 0.f);
        a = fdot2_(q1, u2h2(kv.y), a);
        a = fdot2_(q2, u2h2(kv.z), a);
        a = fdot2_(q3, u2h2(kv.w), a);
        return a;
    };

    // qe[ty] = q . k2t[ty] (exp2-domain via q scaling)
    float qe0, qe1, qe2;
    {
        uint4 k0v = *reinterpret_cast<const uint4*>((const char*)k2t + 0 * 512 + sub * 16);
        uint4 k1v = *reinterpret_cast<const uint4*>((const char*)k2t + 1 * 512 + sub * 16);
        uint4 k2v = *reinterpret_cast<const uint4*>((const char*)k2t + 2 * 512 + sub * 16);
        qe0 = dot(k0v); qe1 = dot(k1v); qe2 = dot(k2v);
        #pragma unroll
        for (int o = 1; o < 32; o <<= 1) {
            qe0 += __shfl_xor(qe0, o);
            qe1 += __shfl_xor(qe1, o);
            qe2 += __shfl_xor(qe2, o);
        }
    }
    auto qsel = [&](unsigned pk) {
        int ty = pk & 3;
        return (ty == 0) ? qe0 : (ty == 1) ? qe1 : qe2;
    };

    // prologue: pair {beg, beg+1}
    unsigned pkA = pack[beg], pkB = pack[beg + 1];
    uint4 kv = *reinterpret_cast<const uint4*>(qkb + ((g ? pkB : pkA) & ~3u) + 512 + sub * 16);
    float scA = h2f_(scoresb[((pkA & ~3u) >> 4) + lane]);
    float scB = h2f_(scoresb[((pkB & ~3u) >> 4) + lane]);

    float m = -INFINITY, s = 0.f, acc = 0.f;

    for (int i = beg; i < end; i += 2) {
        int inext = (i + 2 < end) ? i + 2 : i;
        unsigned npA = pack[inext], npB = pack[inext + 1];
        uint4 nkv = *reinterpret_cast<const uint4*>(qkb + ((g ? npB : npA) & ~3u) + 512 + sub * 16);
        float nsA = h2f_(scoresb[((npA & ~3u) >> 4) + lane]);
        float nsB = h2f_(scoresb[((npB & ~3u) >> 4) + lane]);

        float a = dot(kv);
        #pragma unroll
        for (int o = 1; o < 32; o <<= 1) a += __shfl_xor(a, o);
        float other = __shfl_xor(a, 32);
        float aA = (g ? other : a) + qsel(pkA);
        float aB = (g ? a : other) + qsel(pkB);
        if (i + 1 >= end) aB = -INFINITY;     // odd tail

        float nm = fmaxf(m, fmaxf(aA, aB));
        float c_ = exp2f(m - nm);             // first iter: exp2(-inf)=0
        float w0 = exp2f(aA - nm);
        float w1 = exp2f(aB - nm);
        s = s * c_ + w0 + w1;
        acc = fmaf(acc, c_, fmaf(w0, scA, w1 * scB));
        m = nm;

        pkA = npA; pkB = npB; kv = nkv; scA = nsA; scB = nsB;
    }
    out[(size_t)d * CC + lane] = acc / s;
}

extern "C" void kernel_launch(void* const* d_in, const int* in_sizes, int n_in,
                              void* d_out, int out_size, void* d_ws, size_t ws_size,
                              hipStream_t stream) {
    const float* embedding = (const float*)d_in[0];
    const float* scores    = (const float*)d_in[1];
    const int*   src       = (const int*)d_in[2];
    const int*   dst       = (const int*)d_in[3];
    const int*   typ       = (const int*)d_in[4];
    const float* W1  = (const float*)d_in[5];
    const float* b1  = (const float*)d_in[6];
    const float* W2  = (const float*)d_in[7];
    const float* b2  = (const float*)d_in[8];
    const float* ln_g = (const float*)d_in[9];
    const float* ln_b = (const float*)d_in[10];
    const float* Wl  = (const float*)d_in[11];
    const float* bl  = (const float*)d_in[12];
    const float* Wr  = (const float*)d_in[13];
    const float* br  = (const float*)d_in[14];
    const float* We  = (const float*)d_in[15];
    const float* be  = (const float*)d_in[16];
    const float* emb_table = (const float*)d_in[17];
    float* out = (float*)d_out;
    (void)in_sizes; (void)n_in; (void)out_size; (void)ws_size;

    // ---- workspace carve-up (256-aligned chunks) ----
    char* w = (char*)d_ws;
    auto take = [&](size_t bytes) {
        char* p = w;
        w += (bytes + 255) & ~(size_t)255;
        return p;
    };
    unsigned short* embA = (unsigned short*)take((size_t)NPAD * HH * 2);
    unsigned short* hpre = (unsigned short*)take((size_t)NPAD * HH * 2);
    // BIG buffer: serves Gch [NPAD][1024] f16 during the MLP, then its first
    // half is reused as qk [NPAD][512] f16 (Gch is dead once GEMM2 reads it).
    unsigned short* Gch  = (unsigned short*)take((size_t)NPAD * 1024 * 2);
    unsigned short* qk   = Gch;
    unsigned short* W1T  = (unsigned short*)take((size_t)4 * HH * HH * 2);
    unsigned short* W2T  = (unsigned short*)take((size_t)HH * 4 * HH * 2);
    unsigned short* WlrT = (unsigned short*)take((size_t)512 * HH * 2);
    unsigned short* k2t  = (unsigned short*)take(2048);
    unsigned short* scoresb = (unsigned short*)take((size_t)NN * CC * 2);
    float*          uvec = (float*)take(512 * 4);
    float*          vvec = (float*)take(512 * 4);
    int*            cnt  = (int*)take((size_t)NPAD * 4);   // NPAD*4 is 256-aligned
    float*          st1  = (float*)take((size_t)NPAD * 4); // contiguous with cnt
    float*          st2  = (float*)take((size_t)NPAD * 4); // contiguous with st1
    int*            offb = (int*)take((size_t)(NN + 1) * 4);
    int*            cur  = (int*)take((size_t)NN * 4);
    int*            bsum = (int*)take(256 * 4);
    unsigned int*   pack = (unsigned int*)take((size_t)EE * 4 + 64);

    // zero cnt + st1 + st2 in one memset (contiguous NPAD-sized chunks)
    hipMemsetAsync(cnt, 0, (size_t)3 * NPAD * 4, stream);

    // ---- one prep launch: conversions, transposes, k2, u/v ----
    prep_kernel<<<PB7, 256, 0, stream>>>(
        embedding, scores, W1, W2, Wl, Wr, ln_g, ln_b, bl, br, We, be, emb_table,
        embA, scoresb, W1T, W2T, WlrT, k2t, uvec, vvec);

    // ---- CSR build ----
    hist_kernel<<<(EE + 255) / 256, 256, 0, stream>>>(dst, cnt);
    scan_part<<<NB, 256, 0, stream>>>(cnt, offb, bsum);
    scan_sums<<<1, 256, 0, stream>>>(bsum);
    scan_add<<<NB, 256, 0, stream>>>(offb, bsum, cur);
    fill_kernel<<<(EE + 255) / 256, 256, 0, stream>>>(src, dst, typ, cur, pack);

    // ---- MLP (full-grid, no chunking): hpre = gelu(X@W1+b1)@W2+b2 ----
    dim3 g1(4 * HH / 128, NPAD / 128);     // (8, 391)
    mfma_gemm<1, true, false, false><<<g1, 256, 0, stream>>>(
        embA, W1T, b1, Gch, NN, HH, 4 * HH,
        nullptr, nullptr, nullptr, nullptr, nullptr);
    dim3 g2(HH / 128, NPAD / 128);         // (2, 391)
    mfma_gemm<0, true, true, false><<<g2, 256, 0, stream>>>(
        Gch, W2T, b2, hpre, NN, 4 * HH, HH,
        st1, st2, nullptr, nullptr, nullptr);

    // ---- q|k1 projection with fused LayerNorm (qk aliases dead Gch) ----
    dim3 gq(512 / 128, NPAD / 128);        // (4, 391)
    mfma_gemm<0, true, false, true><<<gq, 256, 0, stream>>>(
        hpre, WlrT, vvec, qk, NN, HH, 512,
        nullptr, nullptr, st1, st2, uvec);

    // ---- fused edge phase ----
    fused_edge_kernel<<<(NN + 3) / 4, 256, 0, stream>>>(qk, k2t, offb, pack, scoresb, out);
}

// Round 9
// 379.843 us; speedup vs baseline: 1.1105x; 1.0569x over previous
//
#include <hip/hip_runtime.h>
#include <math.h>

#define NN 50000
#define EE 800000
#define HH 256
#define CC 64
#define NPAD 50048          // NN rounded to 128
#define NB 196              // scan blocks = ceil(NN/256)
#define QSCALE 0.09016843798f   // (1/16) * log2(e): folds 1/sqrt(H) and exp->exp2

typedef _Float16 f16x8 __attribute__((ext_vector_type(8)));
typedef _Float16 h2 __attribute__((ext_vector_type(2)));
typedef float f32x4 __attribute__((ext_vector_type(4)));

// exact tanh-gelu via sigmoid identity: 0.5x(1+tanh(z)) = x / (1 + exp(-2z))
// 2z*log2e = x*(A + B*x^2);  ~7 VALU ops vs ~45 for libm tanhf.
__device__ __forceinline__ float gelu_f(float x) {
    const float A = 2.302118074f;    // 2*log2(e)*sqrt(2/pi)
    const float B = 0.1029439565f;   // A*0.044715
    float u = x * fmaf(B, x * x, A);
    float den = 1.0f + exp2f(-u);
#if __has_builtin(__builtin_amdgcn_rcpf)
    return x * __builtin_amdgcn_rcpf(den);
#else
    return x / den;
#endif
}

__device__ __forceinline__ unsigned short f2h(float x) {
    _Float16 h = (_Float16)x;
    return __builtin_bit_cast(unsigned short, h);
}

__device__ __forceinline__ float h2f_(unsigned short u) {
    return (float)__builtin_bit_cast(_Float16, u);
}

__device__ __forceinline__ h2 u2h2(unsigned int u) {
    return __builtin_bit_cast(h2, u);
}

__device__ __forceinline__ float fdot2_(h2 a, h2 b, float c) {
#if __has_builtin(__builtin_amdgcn_fdot2)
    return __builtin_amdgcn_fdot2(a, b, c, false);
#else
    return c + (float)a[0] * (float)b[0] + (float)a[1] * (float)b[1];
#endif
}

__device__ __forceinline__ void gld_lds16(const void* g, void* l) {
    __builtin_amdgcn_global_load_lds(
        (const __attribute__((address_space(1))) unsigned int*)g,
        (__attribute__((address_space(3))) unsigned int*)l,
        16, 0, 0);
}

// ---------------------------------------------------------------------------
// C[M,Nc] = act(A_f16[M,K] @ BT_f16[Nc,K]^T + bias); 128x128 tile, BK=64,
// 4 waves, 16x16x32 f16 MFMA, global_load_lds, XOR-swizzled LDS.
// (R6 structure: 32KB LDS, ~5 blocks/CU — measured better than 64KB dbuf.)
// STATS:  atomically accumulate per-row sum/sumsq of the output into st1/st2.
// LNFOLD: out = inv*raw - inv*mu*u[col] + bias[col], mu/inv from rs1/rs2.
// ---------------------------------------------------------------------------
template<int ACT, bool OUT_F16, bool STATS, bool LNFOLD>
__global__ __launch_bounds__(256) void mfma_gemm(
    const unsigned short* __restrict__ A,
    const unsigned short* __restrict__ BT,
    const float* __restrict__ bias,
    void* __restrict__ C,
    int M, int K, int Nc,
    float* __restrict__ st1, float* __restrict__ st2,
    const float* __restrict__ rs1, const float* __restrict__ rs2,
    const float* __restrict__ uvec)
{
    __shared__ __align__(16) unsigned char lds[32768]; // A: [0,16K), B: [16K,32K)
    const int t    = threadIdx.x;
    const int lane = t & 63;
    const int wv   = t >> 6;
    const int wr   = wv >> 1, wc = wv & 1;
    const int row0 = blockIdx.y * 128;
    const int col0 = blockIdx.x * 128;

    f32x4 acc[4][4] = {};

    const int srow  = t >> 3;               // 0..31
    const int sslot = t & 7;
    const int schunk = sslot ^ (srow & 7);  // XOR-swizzled k-chunk slot

    const unsigned short* Ab = A  + (size_t)row0 * K;
    const unsigned short* Bb = BT + (size_t)col0 * K;

    for (int k0 = 0; k0 < K; k0 += 64) {
        #pragma unroll
        for (int i = 0; i < 4; ++i)
            gld_lds16(Ab + (size_t)(i * 32 + srow) * K + k0 + schunk * 8,
                      &lds[i * 4096 + t * 16]);
        #pragma unroll
        for (int i = 0; i < 4; ++i)
            gld_lds16(Bb + (size_t)(i * 32 + srow) * K + k0 + schunk * 8,
                      &lds[16384 + i * 4096 + t * 16]);
        __syncthreads();

        #pragma unroll
        for (int kk = 0; kk < 2; ++kk) {
            f16x8 af[4], bf[4];
            #pragma unroll
            for (int m = 0; m < 4; ++m) {
                int r  = wr * 64 + m * 16 + (lane & 15);
                int ch = (kk * 4 + (lane >> 4)) ^ (r & 7);
                af[m] = *reinterpret_cast<const f16x8*>(&lds[r * 128 + ch * 16]);
            }
            #pragma unroll
            for (int n = 0; n < 4; ++n) {
                int r  = wc * 64 + n * 16 + (lane & 15);
                int ch = (kk * 4 + (lane >> 4)) ^ (r & 7);
                bf[n] = *reinterpret_cast<const f16x8*>(&lds[16384 + r * 128 + ch * 16]);
            }
            #pragma unroll
            for (int m = 0; m < 4; ++m)
                #pragma unroll
                for (int n = 0; n < 4; ++n)
                    acc[m][n] = __builtin_amdgcn_mfma_f32_16x16x32_f16(
                        af[m], bf[n], acc[m][n], 0, 0, 0);
        }
        __syncthreads();
    }

    float bv[4], uv_[4];
    #pragma unroll
    for (int n = 0; n < 4; ++n) {
        int col = col0 + wc * 64 + n * 16 + (lane & 15);
        bv[n] = bias[col];
        if (LNFOLD) uv_[n] = uvec[col];
    }

    #pragma unroll
    for (int m = 0; m < 4; ++m) {
        #pragma unroll
        for (int rg = 0; rg < 4; ++rg) {
            int row = row0 + wr * 64 + m * 16 + (lane >> 4) * 4 + rg;
            float inv = 0.f, nmu = 0.f;
            if (LNFOLD) {
                float S1 = rs1[row], S2 = rs2[row];
                float mu = S1 * (1.0f / HH);
                float var = S2 * (1.0f / HH) - mu * mu;
                inv = rsqrtf(var + 1e-5f);
                nmu = inv * mu;
            }
            float s1l = 0.f, s2l = 0.f;
            #pragma unroll
            for (int n = 0; n < 4; ++n) {
                float v;
                if (LNFOLD) v = fmaf(inv, acc[m][n][rg], fmaf(-nmu, uv_[n], bv[n]));
                else        v = acc[m][n][rg] + bv[n];
                if (ACT) v = gelu_f(v);
                if (STATS) { s1l += v; s2l += v * v; }
                if (row < M) {
                    int col = col0 + wc * 64 + n * 16 + (lane & 15);
                    if (OUT_F16) ((unsigned short*)C)[(size_t)row * Nc + col] = f2h(v);
                    else         ((float*)C)[(size_t)row * Nc + col] = v;
                }
            }
            if (STATS) {
                #pragma unroll
                for (int o = 1; o < 16; o <<= 1) {
                    s1l += __shfl_xor(s1l, o);
                    s2l += __shfl_xor(s2l, o);
                }
                if ((lane & 15) == 0 && row < M) {
                    atomicAdd(&st1[row], s1l);
                    atomicAdd(&st2[row], s2l);
                }
            }
        }
    }
}

// ---------------------------------------------------------------------------
// prep mega-kernel: f2h(embedding), f2h(scores), W1T, W2T, WlrT (g-folded,
// q-half scaled by QSCALE), k2 table, u/v fold vectors — one launch.
// ---------------------------------------------------------------------------
#define PB0 12500                 // embedding f2h   (NN*HH/4/256)
#define PB1 (PB0 + 3125)          // scores f2h
#define PB2 (PB1 + 1024)          // W1T
#define PB3 (PB2 + 1024)          // W2T
#define PB4 (PB3 + 256)           // WlT'
#define PB5 (PB4 + 256)           // WrT'
#define PB6 (PB5 + 3)             // k2
#define PB7 (PB6 + 2)             // u/v
__global__ __launch_bounds__(256) void prep_kernel(
    const float* __restrict__ embedding, const float* __restrict__ scores,
    const float* __restrict__ W1, const float* __restrict__ W2,
    const float* __restrict__ Wl, const float* __restrict__ Wr,
    const float* __restrict__ ln_g, const float* __restrict__ ln_b,
    const float* __restrict__ bl, const float* __restrict__ br,
    const float* __restrict__ We, const float* __restrict__ be,
    const float* __restrict__ emb_table,
    unsigned short* __restrict__ embA, unsigned short* __restrict__ scoresb,
    unsigned short* __restrict__ W1T, unsigned short* __restrict__ W2T,
    unsigned short* __restrict__ WlrT, unsigned short* __restrict__ k2t,
    float* __restrict__ uvec, float* __restrict__ vvec)
{
    const int gb = blockIdx.x, t = threadIdx.x;
    if (gb < PB0) {
        int i = gb * 256 + t;
        float4 v = reinterpret_cast<const float4*>(embedding)[i];
        ushort4 o; o.x = f2h(v.x); o.y = f2h(v.y); o.z = f2h(v.z); o.w = f2h(v.w);
        reinterpret_cast<ushort4*>(embA)[i] = o;
    } else if (gb < PB1) {
        int i = (gb - PB0) * 256 + t;
        float4 v = reinterpret_cast<const float4*>(scores)[i];
        ushort4 o; o.x = f2h(v.x); o.y = f2h(v.y); o.z = f2h(v.z); o.w = f2h(v.w);
        reinterpret_cast<ushort4*>(scoresb)[i] = o;
    } else if (gb < PB2) {
        int o = (gb - PB1) * 256 + t;          // W1T[c][r], c=o>>8
        int c = o >> 8, r = o & 255;
        W1T[o] = f2h(W1[r * 1024 + c]);
    } else if (gb < PB3) {
        int o = (gb - PB2) * 256 + t;          // W2T[c][r], c=o>>10
        int c = o >> 10, r = o & 1023;
        W2T[o] = f2h(W2[r * 256 + c]);
    } else if (gb < PB4) {
        int o = (gb - PB3) * 256 + t;
        int c = o >> 8, r = o & 255;
        WlrT[o] = f2h(Wl[r * 256 + c] * ln_g[r] * QSCALE);
    } else if (gb < PB5) {
        int o = (gb - PB4) * 256 + t;
        int c = o >> 8, r = o & 255;
        WlrT[65536 + o] = f2h(Wr[r * 256 + c] * ln_g[r]);
    } else if (gb < PB6) {
        int ty = gb - PB5;
        float a = be[t];
        #pragma unroll
        for (int f = 0; f < 20; ++f)
            a += gelu_f(emb_table[ty * 20 + f]) * We[f * 256 + t];
        k2t[ty * 256 + t] = f2h(a);
    } else {
        int c = (gb - PB6) * 256 + t;          // 0..511
        int cc = c & 255;
        const float* W = (c < 256) ? Wl : Wr;
        float u = 0.f, v = 0.f;
        for (int j = 0; j < 256; ++j) {
            float w = W[j * 256 + cc];
            u += ln_g[j] * w;
            v += ln_b[j] * w;
        }
        float sc = (c < 256) ? QSCALE : 1.0f;
        uvec[c] = u * sc;
        vvec[c] = (v + ((c < 256) ? bl[cc] : br[cc])) * sc;
    }
}

// ---- CSR build ----
__global__ void hist_kernel(const int* __restrict__ dst, int* __restrict__ cnt)
{
    int e = blockIdx.x * 256 + threadIdx.x;
    if (e < EE) atomicAdd(&cnt[dst[e]], 1);
}

__global__ __launch_bounds__(256) void scan_part(
    const int* __restrict__ cnt, int* __restrict__ off, int* __restrict__ bsum)
{
    int b = blockIdx.x, t = threadIdx.x;
    int idx = b * 256 + t;
    int v = (idx < NN) ? cnt[idx] : 0;
    int inc = v;
    #pragma unroll
    for (int o = 1; o < 64; o <<= 1) {
        int u = __shfl_up(inc, o);
        if ((t & 63) >= o) inc += u;
    }
    __shared__ int wt[4];
    if ((t & 63) == 63) wt[t >> 6] = inc;
    __syncthreads();
    int wo = 0;
    #pragma unroll
    for (int w = 0; w < 4; ++w) if (w < (t >> 6)) wo += wt[w];
    if (idx < NN) off[idx] = wo + inc - v;
    if (t == 255) bsum[b] = wo + inc;
}

__global__ __launch_bounds__(256) void scan_sums(int* __restrict__ bsum)
{
    int t = threadIdx.x;
    int v = (t < NB) ? bsum[t] : 0;
    int inc = v;
    #pragma unroll
    for (int o = 1; o < 64; o <<= 1) {
        int u = __shfl_up(inc, o);
        if ((t & 63) >= o) inc += u;
    }
    __shared__ int wt[4];
    if ((t & 63) == 63) wt[t >> 6] = inc;
    __syncthreads();
    int wo = 0;
    #pragma unroll
    for (int w = 0; w < 4; ++w) if (w < (t >> 6)) wo += wt[w];
    if (t < NB) bsum[t] = wo + inc - v;
}

__global__ void scan_add(int* __restrict__ off, const int* __restrict__ bsum,
                         int* __restrict__ cur)
{
    int b = blockIdx.x, t = threadIdx.x;
    int idx = b * 256 + t;
    if (idx < NN) {
        int o = off[idx] + bsum[b];
        off[idx] = o;
        cur[idx] = o;
    }
    if (idx == 0) off[NN] = EE;
}

// pack entry = (src << 10) | ty  -> byte offset of the qk row, type in low bits
__global__ void fill_kernel(const int* __restrict__ src, const int* __restrict__ dst,
                            const int* __restrict__ typ, int* __restrict__ cur,
                            unsigned int* __restrict__ pack)
{
    int e = blockIdx.x * 256 + threadIdx.x;
    if (e < 8) pack[EE + e] = 0;  // pad slots for unconditional paired reads
    if (e >= EE) return;
    int pos = atomicAdd(&cur[dst[e]], 1);
    pack[pos] = ((unsigned int)src[e] << 10) | (unsigned int)typ[e];
}

// ---------------------------------------------------------------------------
// fused per-dst attention (R6 structure): one wave per node; 2 edges in
// flight with a shared 32-lane dot/reduce, v_dot2 f16 dots, exp2-domain
// online softmax, qe prologue, depth-1 prefetch.
// ---------------------------------------------------------------------------
__global__ __launch_bounds__(256) void fused_edge_kernel(
    const unsigned short* __restrict__ qk,      // f16 [NPAD][512]: [q*QSCALE | k1]
    const unsigned short* __restrict__ k2t,     // f16 [3][256]
    const int* __restrict__ off, const unsigned int* __restrict__ pack,
    const unsigned short* __restrict__ scoresb, // f16 [NN][64]
    float* __restrict__ out)
{
    const int t = threadIdx.x, lane = t & 63;
    const int sub = lane & 31;
    const int g = lane >> 5;
    const int d = blockIdx.x * 4 + (t >> 6);
    if (d >= NN) return;
    const int beg = off[d], end = off[d + 1];
    if (beg == end) { out[(size_t)d * CC + lane] = 0.f; return; }

    const char* qkb = (const char*)qk;

    // q slice: 8 f16 at dims [sub*8, sub*8+8) (duplicated across wave halves)
    uint4 qv = *reinterpret_cast<const uint4*>(qkb + (size_t)d * 1024 + sub * 16);
    h2 q0 = u2h2(qv.x), q1 = u2h2(qv.y), q2 = u2h2(qv.z), q3 = u2h2(qv.w);

    auto dot = [&](uint4 kv) {
        float a = fdot2_(q0, u2h2(kv.x), 0.f);
        a = fdot2_(q1, u2h2(kv.y), a);
        a = fdot2_(q2, u2h2(kv.z), a);
        a = fdot2_(q3, u2h2(kv.w), a);
        return a;
    };

    // qe[ty] = q . k2t[ty] (exp2-domain via q scaling)
    float qe0, qe1, qe2;
    {
        uint4 k0v = *reinterpret_cast<const uint4*>((const char*)k2t + 0 * 512 + sub * 16);
        uint4 k1v = *reinterpret_cast<const uint4*>((const char*)k2t + 1 * 512 + sub * 16);
        uint4 k2v = *reinterpret_cast<const uint4*>((const char*)k2t + 2 * 512 + sub * 16);
        qe0 = dot(k0v); qe1 = dot(k1v); qe2 = dot(k2v);
        #pragma unroll
        for (int o = 1; o < 32; o <<= 1) {
            qe0 += __shfl_xor(qe0, o);
            qe1 += __shfl_xor(qe1, o);
            qe2 += __shfl_xor(qe2, o);
        }
    }
    auto qsel = [&](unsigned pk) {
        int ty = pk & 3;
        return (ty == 0) ? qe0 : (ty == 1) ? qe1 : qe2;
    };

    // prologue: pair {beg, beg+1}
    unsigned pkA = pack[beg], pkB = pack[beg + 1];
    uint4 kv = *reinterpret_cast<const uint4*>(qkb + ((g ? pkB : pkA) & ~3u) + 512 + sub * 16);
    float scA = h2f_(scoresb[((pkA & ~3u) >> 4) + lane]);
    float scB = h2f_(scoresb[((pkB & ~3u) >> 4) + lane]);

    float m = -INFINITY, s = 0.f, acc = 0.f;

    for (int i = beg; i < end; i += 2) {
        int inext = (i + 2 < end) ? i + 2 : i;
        unsigned npA = pack[inext], npB = pack[inext + 1];
        uint4 nkv = *reinterpret_cast<const uint4*>(qkb + ((g ? npB : npA) & ~3u) + 512 + sub * 16);
        float nsA = h2f_(scoresb[((npA & ~3u) >> 4) + lane]);
        float nsB = h2f_(scoresb[((npB & ~3u) >> 4) + lane]);

        float a = dot(kv);
        #pragma unroll
        for (int o = 1; o < 32; o <<= 1) a += __shfl_xor(a, o);
        float other = __shfl_xor(a, 32);
        float aA = (g ? other : a) + qsel(pkA);
        float aB = (g ? a : other) + qsel(pkB);
        if (i + 1 >= end) aB = -INFINITY;     // odd tail

        float nm = fmaxf(m, fmaxf(aA, aB));
        float c_ = exp2f(m - nm);             // first iter: exp2(-inf)=0
        float w0 = exp2f(aA - nm);
        float w1 = exp2f(aB - nm);
        s = s * c_ + w0 + w1;
        acc = fmaf(acc, c_, fmaf(w0, scA, w1 * scB));
        m = nm;

        pkA = npA; pkB = npB; kv = nkv; scA = nsA; scB = nsB;
    }
    out[(size_t)d * CC + lane] = acc / s;
}

extern "C" void kernel_launch(void* const* d_in, const int* in_sizes, int n_in,
                              void* d_out, int out_size, void* d_ws, size_t ws_size,
                              hipStream_t stream) {
    const float* embedding = (const float*)d_in[0];
    const float* scores    = (const float*)d_in[1];
    const int*   src       = (const int*)d_in[2];
    const int*   dst       = (const int*)d_in[3];
    const int*   typ       = (const int*)d_in[4];
    const float* W1  = (const float*)d_in[5];
    const float* b1  = (const float*)d_in[6];
    const float* W2  = (const float*)d_in[7];
    const float* b2  = (const float*)d_in[8];
    const float* ln_g = (const float*)d_in[9];
    const float* ln_b = (const float*)d_in[10];
    const float* Wl  = (const float*)d_in[11];
    const float* bl  = (const float*)d_in[12];
    const float* Wr  = (const float*)d_in[13];
    const float* br  = (const float*)d_in[14];
    const float* We  = (const float*)d_in[15];
    const float* be  = (const float*)d_in[16];
    const float* emb_table = (const float*)d_in[17];
    float* out = (float*)d_out;
    (void)in_sizes; (void)n_in; (void)out_size; (void)ws_size;

    // ---- workspace carve-up (256-aligned chunks) ----
    char* w = (char*)d_ws;
    auto take = [&](size_t bytes) {
        char* p = w;
        w += (bytes + 255) & ~(size_t)255;
        return p;
    };
    unsigned short* embA = (unsigned short*)take((size_t)NPAD * HH * 2);
    unsigned short* hpre = (unsigned short*)take((size_t)NPAD * HH * 2);
    // BIG buffer: serves Gch [NPAD][1024] f16 during the MLP, then its first
    // half is reused as qk [NPAD][512] f16 (Gch is dead once GEMM2 reads it).
    unsigned short* Gch  = (unsigned short*)take((size_t)NPAD * 1024 * 2);
    unsigned short* qk   = Gch;
    unsigned short* W1T  = (unsigned short*)take((size_t)4 * HH * HH * 2);
    unsigned short* W2T  = (unsigned short*)take((size_t)HH * 4 * HH * 2);
    unsigned short* WlrT = (unsigned short*)take((size_t)512 * HH * 2);
    unsigned short* k2t  = (unsigned short*)take(2048);
    unsigned short* scoresb = (unsigned short*)take((size_t)NN * CC * 2);
    float*          uvec = (float*)take(512 * 4);
    float*          vvec = (float*)take(512 * 4);
    int*            cnt  = (int*)take((size_t)NPAD * 4);   // NPAD*4 is 256-aligned
    float*          st1  = (float*)take((size_t)NPAD * 4); // contiguous with cnt
    float*          st2  = (float*)take((size_t)NPAD * 4); // contiguous with st1
    int*            offb = (int*)take((size_t)(NN + 1) * 4);
    int*            cur  = (int*)take((size_t)NN * 4);
    int*            bsum = (int*)take(256 * 4);
    unsigned int*   pack = (unsigned int*)take((size_t)EE * 4 + 64);

    // zero cnt + st1 + st2 in one memset (contiguous NPAD-sized chunks)
    hipMemsetAsync(cnt, 0, (size_t)3 * NPAD * 4, stream);

    // ---- one prep launch: conversions, transposes, k2, u/v ----
    prep_kernel<<<PB7, 256, 0, stream>>>(
        embedding, scores, W1, W2, Wl, Wr, ln_g, ln_b, bl, br, We, be, emb_table,
        embA, scoresb, W1T, W2T, WlrT, k2t, uvec, vvec);

    // ---- CSR build ----
    hist_kernel<<<(EE + 255) / 256, 256, 0, stream>>>(dst, cnt);
    scan_part<<<NB, 256, 0, stream>>>(cnt, offb, bsum);
    scan_sums<<<1, 256, 0, stream>>>(bsum);
    scan_add<<<NB, 256, 0, stream>>>(offb, bsum, cur);
    fill_kernel<<<(EE + 255) / 256, 256, 0, stream>>>(src, dst, typ, cur, pack);

    // ---- MLP (full-grid, no chunking): hpre = gelu(X@W1+b1)@W2+b2 ----
    dim3 g1(4 * HH / 128, NPAD / 128);     // (8, 391)
    mfma_gemm<1, true, false, false><<<g1, 256, 0, stream>>>(
        embA, W1T, b1, Gch, NN, HH, 4 * HH,
        nullptr, nullptr, nullptr, nullptr, nullptr);
    dim3 g2(HH / 128, NPAD / 128);         // (2, 391)
    mfma_gemm<0, true, true, false><<<g2, 256, 0, stream>>>(
        Gch, W2T, b2, hpre, NN, 4 * HH, HH,
        st1, st2, nullptr, nullptr, nullptr);

    // ---- q|k1 projection with fused LayerNorm (qk aliases dead Gch) ----
    dim3 gq(512 / 128, NPAD / 128);        // (4, 391)
    mfma_gemm<0, true, false, true><<<gq, 256, 0, stream>>>(
        hpre, WlrT, vvec, qk, NN, HH, 512,
        nullptr, nullptr, st1, st2, uvec);

    // ---- fused edge phase ----
    fused_edge_kernel<<<(NN + 3) / 4, 256, 0, stream>>>(qk, k2t, offb, pack, scoresb, out);
}